// Round 6
// baseline (547.900 us; speedup 1.0000x reference)
//
#include <hip/hip_runtime.h>
#include <hip/hip_fp16.h>

#define DIM 64
#define BR 64             // rows per block in spmm2
#define CH 16384          // edges per chunk in sort passes
#define BROWS 512         // rows per bucket
#define BSH 9             // log2(BROWS)
#define CBITS 19          // bits for col index in packed word (N < 2^19)
#define CMASK ((1u << CBITS) - 1u)
#define SCAN_T 256
#define SCAN_I 16
#define SCAN_CHUNK (SCAN_T * SCAN_I)

// ===================== dense CSR build (counting sort) =====================

__global__ void k_cnt(const int* __restrict__ rows, int* __restrict__ cnt,
                      int nchunks, int NB, long long E) {
    extern __shared__ int hist[];
    for (int b = threadIdx.x; b < NB; b += blockDim.x) hist[b] = 0;
    __syncthreads();
    long long beg = (long long)blockIdx.x * CH;
    long long end = beg + CH; if (end > E) end = E;
    for (long long i = beg + threadIdx.x; i < end; i += blockDim.x)
        atomicAdd(&hist[rows[i] >> BSH], 1);
    __syncthreads();
    for (int b = threadIdx.x; b < NB; b += blockDim.x)
        cnt[(long long)b * nchunks + blockIdx.x] = hist[b];
}

__global__ void k_scanA(const int* __restrict__ in, int* __restrict__ partials, long long L) {
    long long base = (long long)blockIdx.x * SCAN_CHUNK + (long long)threadIdx.x * SCAN_I;
    int tsum = 0;
    for (int k = 0; k < SCAN_I; ++k) { long long i = base + k; if (i < L) tsum += in[i]; }
    __shared__ int s[SCAN_T];
    s[threadIdx.x] = tsum; __syncthreads();
    for (int o = SCAN_T / 2; o > 0; o >>= 1) {
        if (threadIdx.x < o) s[threadIdx.x] += s[threadIdx.x + o];
        __syncthreads();
    }
    if (threadIdx.x == 0) partials[blockIdx.x] = s[0];
}

__global__ void k_scanB(int* partials, int nb) {
    if (threadIdx.x == 0 && blockIdx.x == 0) {
        int run = 0;
        for (int i = 0; i < nb; ++i) { int v = partials[i]; partials[i] = run; run += v; }
    }
}

__global__ void k_scanC(int* __restrict__ data, const int* __restrict__ partials, long long L) {
    const int t = threadIdx.x;
    long long base = (long long)blockIdx.x * SCAN_CHUNK + (long long)t * SCAN_I;
    int local[SCAN_I]; int tsum = 0;
    for (int k = 0; k < SCAN_I; ++k) {
        long long i = base + k;
        int d = (i < L) ? data[i] : 0;
        local[k] = tsum; tsum += d;
    }
    __shared__ int s[SCAN_T];
    s[t] = tsum; __syncthreads();
    for (int o = 1; o < SCAN_T; o <<= 1) {
        int v = (t >= o) ? s[t - o] : 0;
        __syncthreads();
        s[t] += v;
        __syncthreads();
    }
    int toff = partials[blockIdx.x] + (s[t] - tsum);
    for (int k = 0; k < SCAN_I; ++k) {
        long long i = base + k;
        if (i < L) data[i] = toff + local[k];
    }
}

__global__ void k_scatter(const int* __restrict__ rows, const int* __restrict__ cols,
                          const int* __restrict__ off, unsigned* __restrict__ ebuf,
                          int nchunks, int NB, long long E) {
    extern __shared__ int cur[];
    for (int b = threadIdx.x; b < NB; b += blockDim.x)
        cur[b] = off[(long long)b * nchunks + blockIdx.x];
    __syncthreads();
    long long beg = (long long)blockIdx.x * CH;
    long long end = beg + CH; if (end > E) end = E;
    for (long long i = beg + threadIdx.x; i < end; i += blockDim.x) {
        int r = rows[i], c = cols[i];
        int p = atomicAdd(&cur[r >> BSH], 1);
        ebuf[p] = ((unsigned)(r & (BROWS - 1)) << CBITS) | (unsigned)c;
    }
}

__global__ void k_finalize(const unsigned* __restrict__ ebuf, const int* __restrict__ off,
                           int* __restrict__ rp, float* __restrict__ dinv,
                           float* __restrict__ dsq, int* __restrict__ colso,
                           int nchunks, int NB, long long N, long long E) {
    __shared__ int deg[BROWS];
    __shared__ int cur[BROWS];
    __shared__ int s[256];
    const int b = blockIdx.x, t = threadIdx.x;
    const long long row0 = (long long)b << BSH;
    const int base = off[(long long)b * nchunks];
    const int bend = (b + 1 < NB) ? off[(long long)(b + 1) * nchunks] : (int)E;
    deg[t] = 0; deg[t + 256] = 0;
    __syncthreads();
    for (int i = base + t; i < bend; i += 256)
        atomicAdd(&deg[ebuf[i] >> CBITS], 1);
    __syncthreads();
    int d0 = deg[2 * t], d1 = deg[2 * t + 1];
    s[t] = d0 + d1;
    __syncthreads();
    for (int o = 1; o < 256; o <<= 1) {
        int v = (t >= o) ? s[t - o] : 0;
        __syncthreads();
        s[t] += v;
        __syncthreads();
    }
    int excl = s[t] - (d0 + d1);
    int p0 = base + excl, p1 = p0 + d0;
    cur[2 * t] = p0; cur[2 * t + 1] = p1;
    long long r0 = row0 + 2 * t, r1 = r0 + 1;
    if (r0 < N) {
        rp[r0] = p0;
        dinv[r0] = d0 > 0 ? rsqrtf((float)d0) : 0.0f;
        dsq[r0]  = sqrtf((float)d0);
    }
    if (r1 < N) {
        rp[r1] = p1;
        dinv[r1] = d1 > 0 ? rsqrtf((float)d1) : 0.0f;
        dsq[r1]  = sqrtf((float)d1);
    }
    if (b == 0 && t == 0) rp[N] = (int)E;
    __syncthreads();
    for (int i = base + t; i < bend; i += 256) {
        unsigned w = ebuf[i];
        int lr = (int)(w >> CBITS);
        int c  = (int)(w & CMASK);
        int p = atomicAdd(&cur[lr], 1);
        colso[p] = c;
    }
}

// y0 = D^-1/2 * concat(ue, ie), fp16; float4 in -> 2x half2 (8B) out
__global__ void k_prep(const float4* __restrict__ ue4, const float4* __restrict__ ie4,
                       const float* __restrict__ dinv, int2* __restrict__ yh4,
                       long long NU4, long long total4) {
    long long i = (long long)blockIdx.x * blockDim.x + threadIdx.x;
    if (i >= total4) return;
    float4 v = (i < NU4) ? ue4[i] : ie4[i - NU4];
    float d = dinv[i >> 4];
    __half2 h01 = __floats2half2_rn(v.x * d, v.y * d);
    __half2 h23 = __floats2half2_rn(v.z * d, v.w * d);
    int2 w;
    w.x = *reinterpret_cast<int*>(&h01);
    w.y = *reinterpret_cast<int*>(&h23);
    yh4[i] = w;
}

// ==================== edge-streaming SpMM (LDS accumulate) ====================
// Block owns BR=64 consecutive rows (fp32 LDS acc tile 64x64 = 16 KB).
// 4 waves each stream a contiguous quarter of the block's CSR edge range:
// scalar colso loads (sequential -> constant cache), 8 gathers in flight
// across row boundaries; register partial sum flushed to LDS (ds atomicAdd)
// only on row change. Dense epilogue from LDS.
// FINAL==0: y_dst[r] = s * dinv[r]^2
// FINAL==1: acc[r] = (e0 + (y1+y2)*dsq[r] + s*dinv[r]) * scale
template<int FINAL>
__global__ void k_spmm2(const int* __restrict__ rp, const int* __restrict__ colso,
                        const float* __restrict__ dinv, const float* __restrict__ dsq,
                        const __half* __restrict__ src,
                        const __half* __restrict__ y1, const __half* __restrict__ y2,
                        const float* __restrict__ ue, const float* __restrict__ ie,
                        __half* __restrict__ dsth, float* __restrict__ accb,
                        long long N, long long NU, float scale) {
    __shared__ float accs[BR][DIM];
    __shared__ int srp[BR + 1];
    const int t = threadIdx.x;
    const int lane = t & 63;
    const int wid = __builtin_amdgcn_readfirstlane(t >> 6);
    const int r0 = blockIdx.x * BR;
    if (r0 >= (int)N) return;
    int rN = (int)N - r0; if (rN > BR) rN = BR;

    for (int i = t; i <= rN; i += 256) srp[i] = rp[r0 + i];
    float* af = &accs[0][0];
    #pragma unroll
    for (int i = 0; i < (BR * DIM) / 256; ++i) af[t + i * 256] = 0.0f;
    __syncthreads();

    const int eBeg = __builtin_amdgcn_readfirstlane(srp[0]);
    const int eEnd = __builtin_amdgcn_readfirstlane(srp[rN]);
    const int q = ((eEnd - eBeg) + 3) >> 2;
    int a = eBeg + wid * q;
    int b = a + q; if (b > eEnd) b = eEnd;

    if (a < b) {
        int cur = 0;
        int rowend = __builtin_amdgcn_readfirstlane(srp[1]);
        while (rowend <= a) { ++cur; rowend = __builtin_amdgcn_readfirstlane(srp[cur + 1]); }
        float sreg = 0.0f;
        int e = a;
        while (e + 8 <= b) {
            int c0 = colso[e + 0], c1 = colso[e + 1], c2 = colso[e + 2], c3 = colso[e + 3];
            int c4 = colso[e + 4], c5 = colso[e + 5], c6 = colso[e + 6], c7 = colso[e + 7];
            float g0 = __half2float(src[((long long)c0 << 6) + lane]);
            float g1 = __half2float(src[((long long)c1 << 6) + lane]);
            float g2 = __half2float(src[((long long)c2 << 6) + lane]);
            float g3 = __half2float(src[((long long)c3 << 6) + lane]);
            float g4 = __half2float(src[((long long)c4 << 6) + lane]);
            float g5 = __half2float(src[((long long)c5 << 6) + lane]);
            float g6 = __half2float(src[((long long)c6 << 6) + lane]);
            float g7 = __half2float(src[((long long)c7 << 6) + lane]);
            #define STEP(K, G) \
                while (e + (K) >= rowend) { \
                    if (sreg != 0.0f) atomicAdd(&accs[cur][lane], sreg); \
                    sreg = 0.0f; ++cur; \
                    rowend = __builtin_amdgcn_readfirstlane(srp[cur + 1]); \
                } \
                sreg += (G);
            STEP(0, g0) STEP(1, g1) STEP(2, g2) STEP(3, g3)
            STEP(4, g4) STEP(5, g5) STEP(6, g6) STEP(7, g7)
            e += 8;
        }
        for (; e < b; ++e) {
            while (e >= rowend) {
                if (sreg != 0.0f) atomicAdd(&accs[cur][lane], sreg);
                sreg = 0.0f; ++cur;
                rowend = __builtin_amdgcn_readfirstlane(srp[cur + 1]);
            }
            sreg += __half2float(src[((long long)colso[e] << 6) + lane]);
        }
        if (sreg != 0.0f) atomicAdd(&accs[cur][lane], sreg);
        #undef STEP
    }
    __syncthreads();

    // epilogue: each wave writes BR/4 consecutive rows
    #pragma unroll
    for (int i = 0; i < BR / 4; ++i) {
        int lr = wid * (BR / 4) + i;
        int row = r0 + lr;
        if (row >= (int)N) break;
        float s  = accs[lr][lane];
        float dr = dinv[row];
        long long o = ((long long)row << 6) + lane;
        if (!FINAL) {
            dsth[o] = __float2half(s * dr * dr);
        } else {
            float e0 = (row < (int)NU) ? ue[o] : ie[o - (NU << 6)];
            float yv = __half2float(y1[o]) + __half2float(y2[o]);
            accb[o] = (e0 + yv * dsq[row] + s * dr) * scale;
        }
    }
}

// ============================ fallback (atomic) ============================

__global__ void lgcn_init(const float4* __restrict__ ue, const float4* __restrict__ ie,
                          float4* __restrict__ cur, float4* __restrict__ acc,
                          long long n_user_v4, long long total_v4) {
    long long idx = (long long)blockIdx.x * blockDim.x + threadIdx.x;
    long long stride = (long long)gridDim.x * blockDim.x;
    for (long long i = idx; i < total_v4; i += stride) {
        float4 v = (i < n_user_v4) ? ue[i] : ie[i - n_user_v4];
        cur[i] = v; acc[i] = v;
    }
}

__global__ void lgcn_spmm(const float* __restrict__ vals, const int* __restrict__ rows,
                          const int* __restrict__ cols, const float* __restrict__ cur,
                          float* __restrict__ next, long long nE) {
    long long tid = (long long)blockIdx.x * blockDim.x + threadIdx.x;
    long long stride = (long long)gridDim.x * blockDim.x;
    long long total = nE << 6;
    for (long long i = tid; i < total; i += stride) {
        long long e = i >> 6;
        int d = (int)(i & 63);
        float m = vals[e] * cur[((long long)cols[e] << 6) + d];
        atomicAdd(&next[((long long)rows[e] << 6) + d], m);
    }
}

__global__ void lgcn_acc_add(float4* __restrict__ acc, const float4* __restrict__ nxt,
                             long long total_v4) {
    long long idx = (long long)blockIdx.x * blockDim.x + threadIdx.x;
    long long stride = (long long)gridDim.x * blockDim.x;
    for (long long i = idx; i < total_v4; i += stride) {
        float4 a = acc[i]; float4 b = nxt[i];
        a.x += b.x; a.y += b.y; a.z += b.z; a.w += b.w;
        acc[i] = a;
    }
}

__global__ void lgcn_acc_add_scale(float4* __restrict__ acc, const float4* __restrict__ nxt,
                                   float s, long long total_v4) {
    long long idx = (long long)blockIdx.x * blockDim.x + threadIdx.x;
    long long stride = (long long)gridDim.x * blockDim.x;
    for (long long i = idx; i < total_v4; i += stride) {
        float4 a = acc[i]; float4 b = nxt[i];
        a.x = (a.x + b.x) * s; a.y = (a.y + b.y) * s;
        a.z = (a.z + b.z) * s; a.w = (a.w + b.w) * s;
        acc[i] = a;
    }
}

// ============================ launch ============================

extern "C" void kernel_launch(void* const* d_in, const int* in_sizes, int n_in,
                              void* d_out, int out_size, void* d_ws, size_t ws_size,
                              hipStream_t stream) {
    const float* ue   = (const float*)d_in[0];
    const float* ie   = (const float*)d_in[1];
    const float* vals = (const float*)d_in[2];
    const int*   rows = (const int*)d_in[3];
    const int*   cols = (const int*)d_in[4];
    const int n_layers = 3;   // fixed by problem; grid shapes must be host-known

    const long long n_users = in_sizes[0] / DIM;
    const long long n_items = in_sizes[1] / DIM;
    const long long E       = in_sizes[2];
    const long long N       = n_users + n_items;
    const long long nElem   = N * DIM;
    const long long nV4     = nElem / 4;
    const long long nUserV4 = (n_users * DIM) / 4;

    float* acc = (float*)d_out;
    const int tb = 256;

    const int nchunks = (int)((E + CH - 1) / CH);
    const int NB      = (int)((N + BROWS - 1) / BROWS);
    const long long L = (long long)NB * nchunks;
    const int nbs     = (int)((L + SCAN_CHUNK - 1) / SCAN_CHUNK);

    // ws: yh0,yh1,yh2 (fp16), colso, rp, dinv, dsq, cnt, partials. ebuf overlays yh0.
    size_t need = (size_t)nElem * 2 * 3
                + (size_t)(E + (N + 1) + 2 * N + L + nbs + 64) * 4;

    if (ws_size >= need && N < (1LL << CBITS)) {
        char* p = (char*)d_ws;
        __half* yh0  = (__half*)p;                 p += (size_t)nElem * 2;
        __half* yh1  = (__half*)p;                 p += (size_t)nElem * 2;
        __half* yh2  = (__half*)p;                 p += (size_t)nElem * 2;
        int*   colso = (int*)p;                    p += (size_t)E * 4;
        int*   rp    = (int*)p;                    p += (size_t)(N + 1) * 4;
        float* dinv  = (float*)p;                  p += (size_t)N * 4;
        float* dsq   = (float*)p;                  p += (size_t)N * 4;
        int*   cnt   = (int*)p;                    p += (size_t)L * 4;
        int*   partials = (int*)p;
        unsigned* ebuf = (unsigned*)yh0;           // dead before k_prep writes yh0

        k_cnt<<<nchunks, tb, NB * 4, stream>>>(rows, cnt, nchunks, NB, E);
        k_scanA<<<nbs, SCAN_T, 0, stream>>>(cnt, partials, L);
        k_scanB<<<1, 64, 0, stream>>>(partials, nbs);
        k_scanC<<<nbs, SCAN_T, 0, stream>>>(cnt, partials, L);
        k_scatter<<<nchunks, tb, NB * 4, stream>>>(rows, cols, cnt, ebuf, nchunks, NB, E);
        k_finalize<<<NB, tb, 0, stream>>>(ebuf, cnt, rp, dinv, dsq, colso, nchunks, NB, N, E);

        long long total4 = nElem / 4, NU4 = n_users * (DIM / 4);
        int gprep = (int)((total4 + tb - 1) / tb);
        k_prep<<<gprep, tb, 0, stream>>>((const float4*)ue, (const float4*)ie,
                                         dinv, (int2*)yh0, NU4, total4);

        const int gspmm = (int)((N + BR - 1) / BR);
        // layer 1: y0 -> y1
        k_spmm2<0><<<gspmm, tb, 0, stream>>>(rp, colso, dinv, dsq, yh0,
                                             nullptr, nullptr, nullptr, nullptr,
                                             yh1, nullptr, N, n_users, 0.0f);
        // layer 2: y1 -> y2
        k_spmm2<0><<<gspmm, tb, 0, stream>>>(rp, colso, dinv, dsq, yh1,
                                             nullptr, nullptr, nullptr, nullptr,
                                             yh2, nullptr, N, n_users, 0.0f);
        // layer 3 fused final: gather y2; acc = (e0 + (y1+y2)*dsq + s*dinv)/4
        k_spmm2<1><<<gspmm, tb, 0, stream>>>(rp, colso, dinv, dsq, yh2,
                                             yh1, yh2, ue, ie,
                                             nullptr, acc, N, n_users,
                                             1.0f / (float)(n_layers + 1));
    } else {
        // fallback: atomic scatter path (round-1 kernel)
        float* cur = (float*)d_ws;
        float* nxt = cur + nElem;
        int gridInit = (int)((nV4 + tb - 1) / tb); if (gridInit > 4096) gridInit = 4096;
        lgcn_init<<<gridInit, tb, 0, stream>>>((const float4*)ue, (const float4*)ie,
                                               (float4*)cur, (float4*)acc, nUserV4, nV4);
        for (int l = 0; l < n_layers; ++l) {
            hipMemsetAsync(nxt, 0, (size_t)nElem * 4, stream);
            lgcn_spmm<<<8192, tb, 0, stream>>>(vals, rows, cols, cur, nxt, E);
            if (l == n_layers - 1) {
                lgcn_acc_add_scale<<<gridInit, tb, 0, stream>>>(
                    (float4*)acc, (const float4*)nxt, 1.0f / (float)(n_layers + 1), nV4);
            } else {
                lgcn_acc_add<<<gridInit, tb, 0, stream>>>((float4*)acc, (const float4*)nxt, nV4);
            }
            float* t = cur; cur = nxt; nxt = t;
        }
    }
}

// Round 7
// 483.419 us; speedup vs baseline: 1.1334x; 1.1334x over previous
//
#include <hip/hip_runtime.h>
#include <hip/hip_fp16.h>

#define DIM 64
#define RW 8              // rows per wave in streaming spmm
#define CH 4096           // edges per chunk in sort passes
#define BROWS 256         // rows per bucket
#define BSH 8             // log2(BROWS)
#define CBITS 19          // bits for col index in packed word (N < 2^19)
#define CMASK ((1u << CBITS) - 1u)
#define SCAN_T 256
#define SCAN_I 16
#define SCAN_CHUNK (SCAN_T * SCAN_I)

// ===================== dense CSR build (counting sort) =====================

__global__ void k_cnt(const int* __restrict__ rows, int* __restrict__ cnt,
                      int nchunks, int NB, long long E) {
    extern __shared__ int hist[];
    for (int b = threadIdx.x; b < NB; b += blockDim.x) hist[b] = 0;
    __syncthreads();
    long long beg = (long long)blockIdx.x * CH;
    long long end = beg + CH; if (end > E) end = E;
    for (long long i = beg + threadIdx.x; i < end; i += blockDim.x)
        atomicAdd(&hist[rows[i] >> BSH], 1);
    __syncthreads();
    for (int b = threadIdx.x; b < NB; b += blockDim.x)
        cnt[(long long)b * nchunks + blockIdx.x] = hist[b];
}

__global__ void k_scanA(const int* __restrict__ in, int* __restrict__ partials, long long L) {
    long long base = (long long)blockIdx.x * SCAN_CHUNK + (long long)threadIdx.x * SCAN_I;
    int tsum = 0;
    for (int k = 0; k < SCAN_I; ++k) { long long i = base + k; if (i < L) tsum += in[i]; }
    __shared__ int s[SCAN_T];
    s[threadIdx.x] = tsum; __syncthreads();
    for (int o = SCAN_T / 2; o > 0; o >>= 1) {
        if (threadIdx.x < o) s[threadIdx.x] += s[threadIdx.x + o];
        __syncthreads();
    }
    if (threadIdx.x == 0) partials[blockIdx.x] = s[0];
}

__global__ void k_scanB(int* partials, int nb) {
    if (threadIdx.x == 0 && blockIdx.x == 0) {
        int run = 0;
        for (int i = 0; i < nb; ++i) { int v = partials[i]; partials[i] = run; run += v; }
    }
}

__global__ void k_scanC(int* __restrict__ data, const int* __restrict__ partials, long long L) {
    const int t = threadIdx.x;
    long long base = (long long)blockIdx.x * SCAN_CHUNK + (long long)t * SCAN_I;
    int local[SCAN_I]; int tsum = 0;
    for (int k = 0; k < SCAN_I; ++k) {
        long long i = base + k;
        int d = (i < L) ? data[i] : 0;
        local[k] = tsum; tsum += d;
    }
    __shared__ int s[SCAN_T];
    s[t] = tsum; __syncthreads();
    for (int o = 1; o < SCAN_T; o <<= 1) {
        int v = (t >= o) ? s[t - o] : 0;
        __syncthreads();
        s[t] += v;
        __syncthreads();
    }
    int toff = partials[blockIdx.x] + (s[t] - tsum);
    for (int k = 0; k < SCAN_I; ++k) {
        long long i = base + k;
        if (i < L) data[i] = toff + local[k];
    }
}

__global__ void k_scatter(const int* __restrict__ rows, const int* __restrict__ cols,
                          const int* __restrict__ off, unsigned* __restrict__ ebuf,
                          int nchunks, int NB, long long E) {
    extern __shared__ int cur[];
    for (int b = threadIdx.x; b < NB; b += blockDim.x)
        cur[b] = off[(long long)b * nchunks + blockIdx.x];
    __syncthreads();
    long long beg = (long long)blockIdx.x * CH;
    long long end = beg + CH; if (end > E) end = E;
    for (long long i = beg + threadIdx.x; i < end; i += blockDim.x) {
        int r = rows[i], c = cols[i];
        int p = atomicAdd(&cur[r >> BSH], 1);
        ebuf[p] = ((unsigned)(r & (BROWS - 1)) << CBITS) | (unsigned)c;
    }
}

// One block per bucket (256 rows): row degrees -> rp/dinv/dsq, scatter cols
// into bucket's contiguous colso window, AND fused prep (y0 = dinv*emb fp16).
__global__ void k_finalize(const unsigned* __restrict__ ebuf, const int* __restrict__ off,
                           int* __restrict__ rp, float* __restrict__ dinv,
                           float* __restrict__ dsq, int* __restrict__ colso,
                           const float4* __restrict__ ue4, const float4* __restrict__ ie4,
                           int2* __restrict__ yh4,
                           int nchunks, int NB, long long N, long long NU, long long E) {
    __shared__ int deg[BROWS];
    __shared__ int cur[BROWS];
    __shared__ int s[BROWS];
    __shared__ float sdinv[BROWS];
    const int b = blockIdx.x, t = threadIdx.x;
    const int row0 = b << BSH;
    const int base = off[(long long)b * nchunks];
    const int bend = (b + 1 < NB) ? off[(long long)(b + 1) * nchunks] : (int)E;
    deg[t] = 0;
    __syncthreads();
    for (int i = base + t; i < bend; i += 256)
        atomicAdd(&deg[ebuf[i] >> CBITS], 1);
    __syncthreads();
    int d = deg[t];
    s[t] = d;
    __syncthreads();
    for (int o = 1; o < 256; o <<= 1) {
        int v = (t >= o) ? s[t - o] : 0;
        __syncthreads();
        s[t] += v;
        __syncthreads();
    }
    int p = base + s[t] - d;           // exclusive prefix within bucket
    cur[t] = p;
    float di = d > 0 ? rsqrtf((float)d) : 0.0f;
    sdinv[t] = di;
    int row = row0 + t;
    if (row < (int)N) {
        rp[row] = p;
        dinv[row] = di;
        dsq[row] = sqrtf((float)d);
    }
    if (b == 0 && t == 0) rp[N] = (int)E;
    __syncthreads();
    for (int i = base + t; i < bend; i += 256) {
        unsigned w = ebuf[i];
        int lr = (int)(w >> CBITS);
        int c  = (int)(w & CMASK);
        int pp = atomicAdd(&cur[lr], 1);
        colso[pp] = c;
    }
    // fused prep: 256 rows x 16 float4 each
    for (int i = t; i < BROWS * 16; i += 256) {
        int lr = i >> 4;
        long long row2 = (long long)row0 + lr;
        if (row2 >= N) break;
        long long gi = (row2 << 4) + (i & 15);      // float4 index
        float4 v = (row2 < NU) ? ue4[gi] : ie4[gi - (NU << 4)];
        float dd = sdinv[lr];
        __half2 h01 = __floats2half2_rn(v.x * dd, v.y * dd);
        __half2 h23 = __floats2half2_rn(v.z * dd, v.w * dd);
        int2 w2;
        w2.x = *reinterpret_cast<int*>(&h01);
        w2.y = *reinterpret_cast<int*>(&h23);
        yh4[gi] = w2;
    }
}

// ==================== streaming multi-row SpMM (no LDS) ====================
// Each wave owns RW consecutive rows; streams their union CSR edge range with
// an 8-deep gather pipeline running ACROSS row boundaries. Row bookkeeping is
// wave-uniform (SGPR); flush = direct global store (wave owns its rows).
// FINAL==0: y_dst[r] = s * dinv[r]^2
// FINAL==1: acc[r] = (e0 + (y1+y2)*dsq[r] + s*dinv[r]) * scale
template<int FINAL>
__global__ void k_spmm3(const int* __restrict__ rp, const int* __restrict__ colso,
                        const float* __restrict__ dinv, const float* __restrict__ dsq,
                        const __half* __restrict__ src,
                        const __half* __restrict__ y1, const __half* __restrict__ y2,
                        const float* __restrict__ ue, const float* __restrict__ ie,
                        __half* __restrict__ dsth, float* __restrict__ accb,
                        long long N, long long NU, float scale) {
    const int lane = threadIdx.x & 63;
    const int gw = blockIdx.x * (blockDim.x >> 6) + (threadIdx.x >> 6);
    int r0 = gw * RW;
    if (r0 >= (int)N) return;
    int r1 = r0 + RW; if (r1 > (int)N) r1 = (int)N;
    int cur = __builtin_amdgcn_readfirstlane(r0);
    int e      = rp[cur];
    int rowend = rp[cur + 1];
    const int eEnd = rp[r1];
    float sreg = 0.0f;

    #define FLUSH() { \
        long long o = ((long long)cur << 6) + lane; \
        float dr = dinv[cur]; \
        if (!FINAL) { \
            dsth[o] = __float2half(sreg * dr * dr); \
        } else { \
            float e0 = (cur < (int)NU) ? ue[o] : ie[o - (NU << 6)]; \
            float yv = __half2float(y1[o]) + __half2float(y2[o]); \
            accb[o] = (e0 + yv * dsq[cur] + sreg * dr) * scale; \
        } \
        sreg = 0.0f; }

    #define STEP(K, G) \
        while (e + (K) >= rowend) { FLUSH(); ++cur; rowend = rp[cur + 1]; } \
        sreg += (G);

    while (e + 8 <= eEnd) {
        int c0 = colso[e + 0], c1 = colso[e + 1], c2 = colso[e + 2], c3 = colso[e + 3];
        int c4 = colso[e + 4], c5 = colso[e + 5], c6 = colso[e + 6], c7 = colso[e + 7];
        float g0 = __half2float(src[((long long)c0 << 6) + lane]);
        float g1 = __half2float(src[((long long)c1 << 6) + lane]);
        float g2 = __half2float(src[((long long)c2 << 6) + lane]);
        float g3 = __half2float(src[((long long)c3 << 6) + lane]);
        float g4 = __half2float(src[((long long)c4 << 6) + lane]);
        float g5 = __half2float(src[((long long)c5 << 6) + lane]);
        float g6 = __half2float(src[((long long)c6 << 6) + lane]);
        float g7 = __half2float(src[((long long)c7 << 6) + lane]);
        STEP(0, g0) STEP(1, g1) STEP(2, g2) STEP(3, g3)
        STEP(4, g4) STEP(5, g5) STEP(6, g6) STEP(7, g7)
        e += 8;
    }
    for (; e < eEnd; ++e) {
        while (e >= rowend) { FLUSH(); ++cur; rowend = rp[cur + 1]; }
        sreg += __half2float(src[((long long)colso[e] << 6) + lane]);
    }
    while (cur < r1) { FLUSH(); ++cur; }
    #undef STEP
    #undef FLUSH
}

// ============================ fallback (atomic) ============================

__global__ void lgcn_init(const float4* __restrict__ ue, const float4* __restrict__ ie,
                          float4* __restrict__ cur, float4* __restrict__ acc,
                          long long n_user_v4, long long total_v4) {
    long long idx = (long long)blockIdx.x * blockDim.x + threadIdx.x;
    long long stride = (long long)gridDim.x * blockDim.x;
    for (long long i = idx; i < total_v4; i += stride) {
        float4 v = (i < n_user_v4) ? ue[i] : ie[i - n_user_v4];
        cur[i] = v; acc[i] = v;
    }
}

__global__ void lgcn_spmm(const float* __restrict__ vals, const int* __restrict__ rows,
                          const int* __restrict__ cols, const float* __restrict__ cur,
                          float* __restrict__ next, long long nE) {
    long long tid = (long long)blockIdx.x * blockDim.x + threadIdx.x;
    long long stride = (long long)gridDim.x * blockDim.x;
    long long total = nE << 6;
    for (long long i = tid; i < total; i += stride) {
        long long e = i >> 6;
        int d = (int)(i & 63);
        float m = vals[e] * cur[((long long)cols[e] << 6) + d];
        atomicAdd(&next[((long long)rows[e] << 6) + d], m);
    }
}

__global__ void lgcn_acc_add(float4* __restrict__ acc, const float4* __restrict__ nxt,
                             long long total_v4) {
    long long idx = (long long)blockIdx.x * blockDim.x + threadIdx.x;
    long long stride = (long long)gridDim.x * blockDim.x;
    for (long long i = idx; i < total_v4; i += stride) {
        float4 a = acc[i]; float4 b = nxt[i];
        a.x += b.x; a.y += b.y; a.z += b.z; a.w += b.w;
        acc[i] = a;
    }
}

__global__ void lgcn_acc_add_scale(float4* __restrict__ acc, const float4* __restrict__ nxt,
                                   float s, long long total_v4) {
    long long idx = (long long)blockIdx.x * blockDim.x + threadIdx.x;
    long long stride = (long long)gridDim.x * blockDim.x;
    for (long long i = idx; i < total_v4; i += stride) {
        float4 a = acc[i]; float4 b = nxt[i];
        a.x = (a.x + b.x) * s; a.y = (a.y + b.y) * s;
        a.z = (a.z + b.z) * s; a.w = (a.w + b.w) * s;
        acc[i] = a;
    }
}

// ============================ launch ============================

extern "C" void kernel_launch(void* const* d_in, const int* in_sizes, int n_in,
                              void* d_out, int out_size, void* d_ws, size_t ws_size,
                              hipStream_t stream) {
    const float* ue   = (const float*)d_in[0];
    const float* ie   = (const float*)d_in[1];
    const float* vals = (const float*)d_in[2];
    const int*   rows = (const int*)d_in[3];
    const int*   cols = (const int*)d_in[4];
    const int n_layers = 3;   // fixed by problem; grid shapes must be host-known

    const long long n_users = in_sizes[0] / DIM;
    const long long n_items = in_sizes[1] / DIM;
    const long long E       = in_sizes[2];
    const long long N       = n_users + n_items;
    const long long nElem   = N * DIM;
    const long long nV4     = nElem / 4;
    const long long nUserV4 = (n_users * DIM) / 4;

    float* acc = (float*)d_out;
    const int tb = 256;

    const int nchunks = (int)((E + CH - 1) / CH);
    const int NB      = (int)((N + BROWS - 1) / BROWS);
    const long long L = (long long)NB * nchunks;
    const int nbs     = (int)((L + SCAN_CHUNK - 1) / SCAN_CHUNK);

    // ws: yh0,yh1,yh2 (fp16), colso, rp, dinv, dsq, cnt, partials.
    // ebuf (E*4 = 16 MB) overlays yh2 (38.4 MB) — dead during build; k_finalize
    // reads ebuf and writes yh0/colso only.
    size_t need = (size_t)nElem * 2 * 3
                + (size_t)(E + (N + 1) + 2 * N + L + nbs + 64) * 4;

    if (ws_size >= need && N < (1LL << CBITS)) {
        char* p = (char*)d_ws;
        __half* yh0  = (__half*)p;                 p += (size_t)nElem * 2;
        __half* yh1  = (__half*)p;                 p += (size_t)nElem * 2;
        __half* yh2  = (__half*)p;                 p += (size_t)nElem * 2;
        int*   colso = (int*)p;                    p += (size_t)E * 4;
        int*   rp    = (int*)p;                    p += (size_t)(N + 1) * 4;
        float* dinv  = (float*)p;                  p += (size_t)N * 4;
        float* dsq   = (float*)p;                  p += (size_t)N * 4;
        int*   cnt   = (int*)p;                    p += (size_t)L * 4;
        int*   partials = (int*)p;
        unsigned* ebuf = (unsigned*)yh2;           // dead until spmm layer 2 writes it

        k_cnt<<<nchunks, tb, NB * 4, stream>>>(rows, cnt, nchunks, NB, E);
        k_scanA<<<nbs, SCAN_T, 0, stream>>>(cnt, partials, L);
        k_scanB<<<1, 64, 0, stream>>>(partials, nbs);
        k_scanC<<<nbs, SCAN_T, 0, stream>>>(cnt, partials, L);
        k_scatter<<<nchunks, tb, NB * 4, stream>>>(rows, cols, cnt, ebuf, nchunks, NB, E);
        k_finalize<<<NB, tb, 0, stream>>>(ebuf, cnt, rp, dinv, dsq, colso,
                                          (const float4*)ue, (const float4*)ie, (int2*)yh0,
                                          nchunks, NB, N, n_users, E);

        const int waves  = (int)((N + RW - 1) / RW);
        const int gspmm  = (waves + 3) / 4;         // 4 waves per 256-thread block
        // layer 1: y0 -> y1
        k_spmm3<0><<<gspmm, tb, 0, stream>>>(rp, colso, dinv, dsq, yh0,
                                             nullptr, nullptr, nullptr, nullptr,
                                             yh1, nullptr, N, n_users, 0.0f);
        // layer 2: y1 -> y2
        k_spmm3<0><<<gspmm, tb, 0, stream>>>(rp, colso, dinv, dsq, yh1,
                                             nullptr, nullptr, nullptr, nullptr,
                                             yh2, nullptr, N, n_users, 0.0f);
        // layer 3 fused final: gather y2; acc = (e0 + (y1+y2)*dsq + s*dinv)/4
        k_spmm3<1><<<gspmm, tb, 0, stream>>>(rp, colso, dinv, dsq, yh2,
                                             yh1, yh2, ue, ie,
                                             nullptr, acc, N, n_users,
                                             1.0f / (float)(n_layers + 1));
    } else {
        // fallback: atomic scatter path (round-1 kernel)
        float* cur = (float*)d_ws;
        float* nxt = cur + nElem;
        int gridInit = (int)((nV4 + tb - 1) / tb); if (gridInit > 4096) gridInit = 4096;
        lgcn_init<<<gridInit, tb, 0, stream>>>((const float4*)ue, (const float4*)ie,
                                               (float4*)cur, (float4*)acc, nUserV4, nV4);
        for (int l = 0; l < n_layers; ++l) {
            hipMemsetAsync(nxt, 0, (size_t)nElem * 4, stream);
            lgcn_spmm<<<8192, tb, 0, stream>>>(vals, rows, cols, cur, nxt, E);
            if (l == n_layers - 1) {
                lgcn_acc_add_scale<<<gridInit, tb, 0, stream>>>(
                    (float4*)acc, (const float4*)nxt, 1.0f / (float)(n_layers + 1), nV4);
            } else {
                lgcn_acc_add<<<gridInit, tb, 0, stream>>>((float4*)acc, (const float4*)nxt, nV4);
            }
            float* t = cur; cur = nxt; nxt = t;
        }
    }
}

// Round 9
// 388.603 us; speedup vs baseline: 1.4099x; 1.2440x over previous
//
#include <hip/hip_runtime.h>
#include <hip/hip_fp16.h>

#define DIM 64
#define RW 8              // rows per wave in streaming spmm
#define CH 16384          // edges per chunk in sort passes
#define BROWS 256         // rows per bucket
#define BSH 8             // log2(BROWS)
#define CBITS 19          // bits for col index in packed word (N < 2^19)
#define CMASK ((1u << CBITS) - 1u)
#define SCAN_T 256
#define SCAN_I 16
#define SCAN_CHUNK (SCAN_T * SCAN_I)

typedef float floatx4 __attribute__((ext_vector_type(4)));

__device__ __forceinline__ float4 nt_load_f4(const float4* p) {
    floatx4 v = __builtin_nontemporal_load((const floatx4*)p);
    return make_float4(v.x, v.y, v.z, v.w);
}
__device__ __forceinline__ float nt_load_f(const float* p) {
    return __builtin_nontemporal_load(p);
}
__device__ __forceinline__ void nt_store_f(float v, float* p) {
    __builtin_nontemporal_store(v, p);
}
__device__ __forceinline__ float nt_load_h2f(const __half* p) {
    unsigned short u = __builtin_nontemporal_load((const unsigned short*)p);
    __half h = *reinterpret_cast<__half*>(&u);
    return __half2float(h);
}

// ===================== dense CSR build (counting sort) =====================

__global__ void k_cnt(const int* __restrict__ rows, int* __restrict__ cnt,
                      int nchunks, int NB, long long E) {
    extern __shared__ int hist[];
    for (int b = threadIdx.x; b < NB; b += blockDim.x) hist[b] = 0;
    __syncthreads();
    long long beg = (long long)blockIdx.x * CH;
    long long end = beg + CH; if (end > E) end = E;
    for (long long i = beg + threadIdx.x; i < end; i += blockDim.x)
        atomicAdd(&hist[rows[i] >> BSH], 1);
    __syncthreads();
    for (int b = threadIdx.x; b < NB; b += blockDim.x)
        cnt[(long long)b * nchunks + blockIdx.x] = hist[b];
}

__global__ void k_scanA(const int* __restrict__ in, int* __restrict__ partials, long long L) {
    long long base = (long long)blockIdx.x * SCAN_CHUNK + (long long)threadIdx.x * SCAN_I;
    int tsum = 0;
    for (int k = 0; k < SCAN_I; ++k) { long long i = base + k; if (i < L) tsum += in[i]; }
    __shared__ int s[SCAN_T];
    s[threadIdx.x] = tsum; __syncthreads();
    for (int o = SCAN_T / 2; o > 0; o >>= 1) {
        if (threadIdx.x < o) s[threadIdx.x] += s[threadIdx.x + o];
        __syncthreads();
    }
    if (threadIdx.x == 0) partials[blockIdx.x] = s[0];
}

__global__ void k_scanB(int* partials, int nb) {
    if (threadIdx.x == 0 && blockIdx.x == 0) {
        int run = 0;
        for (int i = 0; i < nb; ++i) { int v = partials[i]; partials[i] = run; run += v; }
    }
}

__global__ void k_scanC(int* __restrict__ data, const int* __restrict__ partials, long long L) {
    const int t = threadIdx.x;
    long long base = (long long)blockIdx.x * SCAN_CHUNK + (long long)t * SCAN_I;
    int local[SCAN_I]; int tsum = 0;
    for (int k = 0; k < SCAN_I; ++k) {
        long long i = base + k;
        int d = (i < L) ? data[i] : 0;
        local[k] = tsum; tsum += d;
    }
    __shared__ int s[SCAN_T];
    s[t] = tsum; __syncthreads();
    for (int o = 1; o < SCAN_T; o <<= 1) {
        int v = (t >= o) ? s[t - o] : 0;
        __syncthreads();
        s[t] += v;
        __syncthreads();
    }
    int toff = partials[blockIdx.x] + (s[t] - tsum);
    for (int k = 0; k < SCAN_I; ++k) {
        long long i = base + k;
        if (i < L) data[i] = toff + local[k];
    }
}

__global__ void k_scatter(const int* __restrict__ rows, const int* __restrict__ cols,
                          const int* __restrict__ off, unsigned* __restrict__ ebuf,
                          int nchunks, int NB, long long E) {
    extern __shared__ int cur[];
    for (int b = threadIdx.x; b < NB; b += blockDim.x)
        cur[b] = off[(long long)b * nchunks + blockIdx.x];
    __syncthreads();
    long long beg = (long long)blockIdx.x * CH;
    long long end = beg + CH; if (end > E) end = E;
    for (long long i = beg + threadIdx.x; i < end; i += blockDim.x) {
        int r = rows[i], c = cols[i];
        int p = atomicAdd(&cur[r >> BSH], 1);
        ebuf[p] = ((unsigned)(r & (BROWS - 1)) << CBITS) | (unsigned)c;
    }
}

// One block per bucket (256 rows): row degrees -> rp/dinv/dsq, scatter cols
// into bucket's contiguous colso window, AND fused prep (y0 = dinv*emb fp16).
__global__ void k_finalize(const unsigned* __restrict__ ebuf, const int* __restrict__ off,
                           int* __restrict__ rp, float* __restrict__ dinv,
                           float* __restrict__ dsq, int* __restrict__ colso,
                           const float4* __restrict__ ue4, const float4* __restrict__ ie4,
                           int2* __restrict__ yh4,
                           int nchunks, int NB, long long N, long long NU, long long E) {
    __shared__ int deg[BROWS];
    __shared__ int cur[BROWS];
    __shared__ int s[BROWS];
    __shared__ float sdinv[BROWS];
    const int b = blockIdx.x, t = threadIdx.x;
    const int row0 = b << BSH;
    const int base = off[(long long)b * nchunks];
    const int bend = (b + 1 < NB) ? off[(long long)(b + 1) * nchunks] : (int)E;
    deg[t] = 0;
    __syncthreads();
    for (int i = base + t; i < bend; i += 256)
        atomicAdd(&deg[ebuf[i] >> CBITS], 1);
    __syncthreads();
    int d = deg[t];
    s[t] = d;
    __syncthreads();
    for (int o = 1; o < 256; o <<= 1) {
        int v = (t >= o) ? s[t - o] : 0;
        __syncthreads();
        s[t] += v;
        __syncthreads();
    }
    int p = base + s[t] - d;           // exclusive prefix within bucket
    cur[t] = p;
    float di = d > 0 ? rsqrtf((float)d) : 0.0f;
    sdinv[t] = di;
    int row = row0 + t;
    if (row < (int)N) {
        rp[row] = p;
        dinv[row] = di;
        dsq[row] = sqrtf((float)d);
    }
    if (b == 0 && t == 0) rp[N] = (int)E;
    __syncthreads();
    for (int i = base + t; i < bend; i += 256) {
        unsigned w = ebuf[i];
        int lr = (int)(w >> CBITS);
        int c  = (int)(w & CMASK);
        int pp = atomicAdd(&cur[lr], 1);
        colso[pp] = c;
    }
    // fused prep: 256 rows x 16 float4 each (nt loads: emb read-once here)
    for (int i = t; i < BROWS * 16; i += 256) {
        int lr = i >> 4;
        long long row2 = (long long)row0 + lr;
        if (row2 >= N) break;
        long long gi = (row2 << 4) + (i & 15);      // float4 index
        float4 v = (row2 < NU) ? nt_load_f4(ue4 + gi)
                               : nt_load_f4(ie4 + (gi - (NU << 4)));
        float dd = sdinv[lr];
        __half2 h01 = __floats2half2_rn(v.x * dd, v.y * dd);
        __half2 h23 = __floats2half2_rn(v.z * dd, v.w * dd);
        int2 w2;
        w2.x = *reinterpret_cast<int*>(&h01);
        w2.y = *reinterpret_cast<int*>(&h23);
        yh4[gi] = w2;
    }
}

// ==================== streaming multi-row SpMM (16-deep, no LDS) ====================
// Each wave owns RW consecutive rows; streams their union CSR edge range with
// a 16-deep gather pipeline running ACROSS row boundaries. Row bookkeeping is
// wave-uniform (SGPR); flush = direct global store (wave owns its rows).
// FINAL==0: y_dst[r] = s * dinv[r]^2
// FINAL==1: acc[r] = (e0 + (y1+y2)*dsq[r] + s*dinv[r]) * scale   (nt load/store)
template<int FINAL>
__global__ void k_spmm4(const int* __restrict__ rp, const int* __restrict__ colso,
                        const float* __restrict__ dinv, const float* __restrict__ dsq,
                        const __half* __restrict__ src,
                        const __half* __restrict__ y1, const __half* __restrict__ y2,
                        const float* __restrict__ ue, const float* __restrict__ ie,
                        __half* __restrict__ dsth, float* __restrict__ accb,
                        long long N, long long NU, float scale) {
    const int lane = threadIdx.x & 63;
    const int gw = blockIdx.x * (blockDim.x >> 6) + (threadIdx.x >> 6);
    int r0 = gw * RW;
    if (r0 >= (int)N) return;
    int r1 = r0 + RW; if (r1 > (int)N) r1 = (int)N;
    int cur = __builtin_amdgcn_readfirstlane(r0);
    int e      = rp[cur];
    int rowend = rp[cur + 1];
    const int eEnd = rp[r1];
    float sreg = 0.0f;

    #define FLUSH() { \
        long long o = ((long long)cur << 6) + lane; \
        float dr = dinv[cur]; \
        if (!FINAL) { \
            dsth[o] = __float2half(sreg * dr * dr); \
        } else { \
            float e0 = (cur < (int)NU) ? nt_load_f(ue + o) \
                                       : nt_load_f(ie + (o - (NU << 6))); \
            float yv = nt_load_h2f(y1 + o) + __half2float(y2[o]); \
            nt_store_f((e0 + yv * dsq[cur] + sreg * dr) * scale, accb + o); \
        } \
        sreg = 0.0f; }

    #define STEP(K, G) \
        while (e + (K) >= rowend) { FLUSH(); ++cur; rowend = rp[cur + 1]; } \
        sreg += (G);

    #define LOADC(K) int c##K = colso[e + (K)];
    #define GATH(K)  float g##K = __half2float(src[((long long)c##K << 6) + lane]);

    while (e + 16 <= eEnd) {
        LOADC(0) LOADC(1) LOADC(2) LOADC(3) LOADC(4) LOADC(5) LOADC(6) LOADC(7)
        LOADC(8) LOADC(9) LOADC(10) LOADC(11) LOADC(12) LOADC(13) LOADC(14) LOADC(15)
        GATH(0) GATH(1) GATH(2) GATH(3) GATH(4) GATH(5) GATH(6) GATH(7)
        GATH(8) GATH(9) GATH(10) GATH(11) GATH(12) GATH(13) GATH(14) GATH(15)
        STEP(0, g0) STEP(1, g1) STEP(2, g2) STEP(3, g3)
        STEP(4, g4) STEP(5, g5) STEP(6, g6) STEP(7, g7)
        STEP(8, g8) STEP(9, g9) STEP(10, g10) STEP(11, g11)
        STEP(12, g12) STEP(13, g13) STEP(14, g14) STEP(15, g15)
        e += 16;
    }
    while (e + 4 <= eEnd) {
        LOADC(0) LOADC(1) LOADC(2) LOADC(3)
        GATH(0) GATH(1) GATH(2) GATH(3)
        STEP(0, g0) STEP(1, g1) STEP(2, g2) STEP(3, g3)
        e += 4;
    }
    for (; e < eEnd; ++e) {
        while (e >= rowend) { FLUSH(); ++cur; rowend = rp[cur + 1]; }
        sreg += __half2float(src[((long long)colso[e] << 6) + lane]);
    }
    while (cur < r1) { FLUSH(); ++cur; }
    #undef STEP
    #undef FLUSH
    #undef LOADC
    #undef GATH
}

// ============================ fallback (atomic) ============================

__global__ void lgcn_init(const float4* __restrict__ ue, const float4* __restrict__ ie,
                          float4* __restrict__ cur, float4* __restrict__ acc,
                          long long n_user_v4, long long total_v4) {
    long long idx = (long long)blockIdx.x * blockDim.x + threadIdx.x;
    long long stride = (long long)gridDim.x * blockDim.x;
    for (long long i = idx; i < total_v4; i += stride) {
        float4 v = (i < n_user_v4) ? ue[i] : ie[i - n_user_v4];
        cur[i] = v; acc[i] = v;
    }
}

__global__ void lgcn_spmm(const float* __restrict__ vals, const int* __restrict__ rows,
                          const int* __restrict__ cols, const float* __restrict__ cur,
                          float* __restrict__ next, long long nE) {
    long long tid = (long long)blockIdx.x * blockDim.x + threadIdx.x;
    long long stride = (long long)gridDim.x * blockDim.x;
    long long total = nE << 6;
    for (long long i = tid; i < total; i += stride) {
        long long e = i >> 6;
        int d = (int)(i & 63);
        float m = vals[e] * cur[((long long)cols[e] << 6) + d];
        atomicAdd(&next[((long long)rows[e] << 6) + d], m);
    }
}

__global__ void lgcn_acc_add(float4* __restrict__ acc, const float4* __restrict__ nxt,
                             long long total_v4) {
    long long idx = (long long)blockIdx.x * blockDim.x + threadIdx.x;
    long long stride = (long long)gridDim.x * blockDim.x;
    for (long long i = idx; i < total_v4; i += stride) {
        float4 a = acc[i]; float4 b = nxt[i];
        a.x += b.x; a.y += b.y; a.z += b.z; a.w += b.w;
        acc[i] = a;
    }
}

__global__ void lgcn_acc_add_scale(float4* __restrict__ acc, const float4* __restrict__ nxt,
                                   float s, long long total_v4) {
    long long idx = (long long)blockIdx.x * blockDim.x + threadIdx.x;
    long long stride = (long long)gridDim.x * blockDim.x;
    for (long long i = idx; i < total_v4; i += stride) {
        float4 a = acc[i]; float4 b = nxt[i];
        a.x = (a.x + b.x) * s; a.y = (a.y + b.y) * s;
        a.z = (a.z + b.z) * s; a.w = (a.w + b.w) * s;
        acc[i] = a;
    }
}

// ============================ launch ============================

extern "C" void kernel_launch(void* const* d_in, const int* in_sizes, int n_in,
                              void* d_out, int out_size, void* d_ws, size_t ws_size,
                              hipStream_t stream) {
    const float* ue   = (const float*)d_in[0];
    const float* ie   = (const float*)d_in[1];
    const float* vals = (const float*)d_in[2];
    const int*   rows = (const int*)d_in[3];
    const int*   cols = (const int*)d_in[4];
    const int n_layers = 3;   // fixed by problem; grid shapes must be host-known

    const long long n_users = in_sizes[0] / DIM;
    const long long n_items = in_sizes[1] / DIM;
    const long long E       = in_sizes[2];
    const long long N       = n_users + n_items;
    const long long nElem   = N * DIM;
    const long long nV4     = nElem / 4;
    const long long nUserV4 = (n_users * DIM) / 4;

    float* acc = (float*)d_out;
    const int tb = 256;

    const int nchunks = (int)((E + CH - 1) / CH);
    const int NB      = (int)((N + BROWS - 1) / BROWS);
    const long long L = (long long)NB * nchunks;
    const int nbs     = (int)((L + SCAN_CHUNK - 1) / SCAN_CHUNK);

    // ws: yh0,yh1,yh2 (fp16), colso, rp, dinv, dsq, cnt, partials.
    // ebuf (E*4 = 16 MB) overlays yh2 (38.4 MB) — dead during build; k_finalize
    // reads ebuf and writes yh0/colso only.
    size_t need = (size_t)nElem * 2 * 3
                + (size_t)(E + (N + 1) + 2 * N + L + nbs + 64) * 4;

    if (ws_size >= need && N < (1LL << CBITS)) {
        char* p = (char*)d_ws;
        __half* yh0  = (__half*)p;                 p += (size_t)nElem * 2;
        __half* yh1  = (__half*)p;                 p += (size_t)nElem * 2;
        __half* yh2  = (__half*)p;                 p += (size_t)nElem * 2;
        int*   colso = (int*)p;                    p += (size_t)E * 4;
        int*   rp    = (int*)p;                    p += (size_t)(N + 1) * 4;
        float* dinv  = (float*)p;                  p += (size_t)N * 4;
        float* dsq   = (float*)p;                  p += (size_t)N * 4;
        int*   cnt   = (int*)p;                    p += (size_t)L * 4;
        int*   partials = (int*)p;
        unsigned* ebuf = (unsigned*)yh2;           // dead until spmm layer 2 writes it

        k_cnt<<<nchunks, tb, NB * 4, stream>>>(rows, cnt, nchunks, NB, E);
        k_scanA<<<nbs, SCAN_T, 0, stream>>>(cnt, partials, L);
        k_scanB<<<1, 64, 0, stream>>>(partials, nbs);
        k_scanC<<<nbs, SCAN_T, 0, stream>>>(cnt, partials, L);
        k_scatter<<<nchunks, tb, NB * 4, stream>>>(rows, cols, cnt, ebuf, nchunks, NB, E);
        k_finalize<<<NB, tb, 0, stream>>>(ebuf, cnt, rp, dinv, dsq, colso,
                                          (const float4*)ue, (const float4*)ie, (int2*)yh0,
                                          nchunks, NB, N, n_users, E);

        const int waves  = (int)((N + RW - 1) / RW);
        const int gspmm  = (waves + 3) / 4;         // 4 waves per 256-thread block
        // layer 1: y0 -> y1
        k_spmm4<0><<<gspmm, tb, 0, stream>>>(rp, colso, dinv, dsq, yh0,
                                             nullptr, nullptr, nullptr, nullptr,
                                             yh1, nullptr, N, n_users, 0.0f);
        // layer 2: y1 -> y2
        k_spmm4<0><<<gspmm, tb, 0, stream>>>(rp, colso, dinv, dsq, yh1,
                                             nullptr, nullptr, nullptr, nullptr,
                                             yh2, nullptr, N, n_users, 0.0f);
        // layer 3 fused final: gather y2; acc = (e0 + (y1+y2)*dsq + s*dinv)/4
        k_spmm4<1><<<gspmm, tb, 0, stream>>>(rp, colso, dinv, dsq, yh2,
                                             yh1, yh2, ue, ie,
                                             nullptr, acc, N, n_users,
                                             1.0f / (float)(n_layers + 1));
    } else {
        // fallback: atomic scatter path (round-1 kernel)
        float* cur = (float*)d_ws;
        float* nxt = cur + nElem;
        int gridInit = (int)((nV4 + tb - 1) / tb); if (gridInit > 4096) gridInit = 4096;
        lgcn_init<<<gridInit, tb, 0, stream>>>((const float4*)ue, (const float4*)ie,
                                               (float4*)cur, (float4*)acc, nUserV4, nV4);
        for (int l = 0; l < n_layers; ++l) {
            hipMemsetAsync(nxt, 0, (size_t)nElem * 4, stream);
            lgcn_spmm<<<8192, tb, 0, stream>>>(vals, rows, cols, cur, nxt, E);
            if (l == n_layers - 1) {
                lgcn_acc_add_scale<<<gridInit, tb, 0, stream>>>(
                    (float4*)acc, (const float4*)nxt, 1.0f / (float)(n_layers + 1), nV4);
            } else {
                lgcn_acc_add<<<gridInit, tb, 0, stream>>>((float4*)acc, (const float4*)nxt, nV4);
            }
            float* t = cur; cur = nxt; nxt = t;
        }
    }
}